// Round 1
// baseline (222.193 us; speedup 1.0000x reference)
//
#include <hip/hip_runtime.h>
#include <math.h>

#define B_G   256
#define IN_D  128
#define FD    256
#define HID   256
#define OUT_D 128
#define TXT   512
#define XKS   136   // X LDS k-stride (ushorts): 272 B/row, 16B-aligned, <=2-way bank

typedef short bf16x8 __attribute__((ext_vector_type(8)));
typedef float f32x4  __attribute__((ext_vector_type(4)));

// ---------------------------------------------------------------------------
// bf16 split helpers (RNE)
// ---------------------------------------------------------------------------
__device__ __forceinline__ unsigned bf_rne(float x) {
    unsigned u = __float_as_uint(x);
    u += 0x7fffu + ((u >> 16) & 1u);
    return u >> 16;
}
__device__ __forceinline__ float bf_to_f(unsigned h) {
    return __uint_as_float(h << 16);
}
__device__ __forceinline__ void split2(float a0, float a1, unsigned& hp, unsigned& lp) {
    unsigned h0 = bf_rne(a0), h1 = bf_rne(a1);
    float r0 = a0 - bf_to_f(h0), r1 = a1 - bf_to_f(h1);
    hp = h0 | (h1 << 16);
    lp = bf_rne(r0) | (bf_rne(r1) << 16);
}

// ---------------------------------------------------------------------------
// Kernel A (grid 261): fused prep.
//  blocks 0..255  : q_b = te@Wq+bq ; qk_b = Wk@q_b ; zero hsum[b]
//  blocks 256..259: split W0 into tight fragment-layout hi/lo bf16 buffers
//                   W0s[kc=4][col=256][kk=32]
//  block  260     : parallel scan of lens -> offsets
// ---------------------------------------------------------------------------
__global__ __launch_bounds__(256) void k_prepA(
    const float* __restrict__ text_emb, const float* __restrict__ Wq,
    const float* __restrict__ bq, const float* __restrict__ Wk,
    const float* __restrict__ W0, const int* __restrict__ lens,
    float* __restrict__ qk, int* __restrict__ offsets, float* __restrict__ hsum,
    unsigned short* __restrict__ W0sH, unsigned short* __restrict__ W0sL)
{
    int blk = blockIdx.x, t = threadIdx.x;
    __shared__ float te[TXT];
    __shared__ float q[FD];
    __shared__ int   sc[B_G];

    if (blk < 256) {
        int b = blk;
        hsum[b * FD + t] = 0.f;
        for (int i = t; i < TXT; i += 256) te[i] = text_emb[(size_t)b * TXT + i];
        __syncthreads();
        float acc = bq[t];
        for (int k = 0; k < TXT; k++) acc = fmaf(te[k], Wq[k * FD + t], acc);
        q[t] = acc;
        __syncthreads();
        float a2 = 0.f;
        for (int f = 0; f < FD; f++) a2 = fmaf(Wk[t * FD + f], q[f], a2);
        qk[b * FD + t] = a2;
    } else if (blk < 260) {
        int e = (blk - 256) * 256 + t;   // 0..1023
        int kc = e >> 8, c = e & 255;
        size_t base = (size_t)(kc * 256 + c) * 32;
        for (int kk = 0; kk < 32; kk++) {
            float v = W0[(size_t)(kc * 32 + kk) * FD + c];
            unsigned h = bf_rne(v);
            float r = v - bf_to_f(h);
            W0sH[base + kk] = (unsigned short)h;
            W0sL[base + kk] = (unsigned short)bf_rne(r);
        }
    } else {
        // parallel inclusive scan of lens (256 elements, 8 steps)
        sc[t] = lens[t];
        __syncthreads();
        for (int d = 1; d < 256; d <<= 1) {
            int v = (t >= d) ? sc[t - d] : 0;
            __syncthreads();
            sc[t] += v;
            __syncthreads();
        }
        offsets[t + 1] = sc[t];
        if (t == 0) offsets[0] = 0;
    }
}

// ---------------------------------------------------------------------------
// K1: bf16x3 MFMA, barrier-free K-loop.  (unchanged)
// ---------------------------------------------------------------------------
__global__ __launch_bounds__(256, 2) void k_l0_mfma(
    const float* __restrict__ X,
    const unsigned short* __restrict__ W0sH, const unsigned short* __restrict__ W0sL,
    const float* __restrict__ b0, const float* __restrict__ qk,
    const int* __restrict__ offsets,
    float* __restrict__ scores, float* __restrict__ hsum)
{
    int b = blockIdx.y;
    int off = offsets[b], len = offsets[b + 1] - off;
    int n0 = blockIdx.x * 64;
    if (n0 >= len) return;
    int nvalid = min(64, len - n0);

    __shared__ __align__(16) unsigned short XsH[64 * XKS], XsL[64 * XKS]; // 2x17408 B
    __shared__ float qks[FD];
    __shared__ float bsh[FD];
    __shared__ float red[4][64];

    int tid = threadIdx.x;
    int lane = tid & 63, w = tid >> 6;
    int ln = lane & 15, quad = lane >> 4;

    qks[tid] = qk[b * FD + tid];
    bsh[tid] = b0[tid];

    // ---- stage X (full K) : thread -> node tid>>2, k-range (tid&3)*32..+32 ----
    {
        int node_s = tid >> 2, ks = (tid & 3) * 32;
        const float* Xr = X + (size_t)(off + n0 + node_s) * IN_D + ks;
        float xv[32];
        if (node_s < nvalid) {
#pragma unroll
            for (int q2 = 0; q2 < 8; q2++) {
                float4 v = ((const float4*)Xr)[q2];
                xv[q2 * 4 + 0] = v.x; xv[q2 * 4 + 1] = v.y;
                xv[q2 * 4 + 2] = v.z; xv[q2 * 4 + 3] = v.w;
            }
        } else {
#pragma unroll
            for (int q2 = 0; q2 < 32; q2++) xv[q2] = 0.f;
        }
#pragma unroll
        for (int g = 0; g < 4; g++) {
            uint4 hq, lq;
            split2(xv[g * 8 + 0], xv[g * 8 + 1], hq.x, lq.x);
            split2(xv[g * 8 + 2], xv[g * 8 + 3], hq.y, lq.y);
            split2(xv[g * 8 + 4], xv[g * 8 + 5], hq.z, lq.z);
            split2(xv[g * 8 + 6], xv[g * 8 + 7], hq.w, lq.w);
            *(uint4*)&XsH[node_s * XKS + ks + g * 8] = hq;
            *(uint4*)&XsL[node_s * XKS + ks + g * 8] = lq;
        }
    }
    __syncthreads();

    f32x4 acc[4][4] = {};
#pragma unroll
    for (int kc = 0; kc < 4; kc++) {
        bf16x8 AH[4], AL[4], BH[4], BL[4];
#pragma unroll
        for (int i = 0; i < 4; i++) {
            AH[i] = *(const bf16x8*)&XsH[(16 * i + ln) * XKS + kc * 32 + quad * 8];
            AL[i] = *(const bf16x8*)&XsL[(16 * i + ln) * XKS + kc * 32 + quad * 8];
        }
#pragma unroll
        for (int j = 0; j < 4; j++) {
            int c = 64 * w + 16 * j + ln;
            size_t base = (size_t)(kc * 256 + c) * 32 + quad * 8;
            BH[j] = *(const bf16x8*)&W0sH[base];
            BL[j] = *(const bf16x8*)&W0sL[base];
        }
#pragma unroll
        for (int i = 0; i < 4; i++)
#pragma unroll
            for (int j = 0; j < 4; j++) {
                acc[i][j] = __builtin_amdgcn_mfma_f32_16x16x32_bf16(AH[i], BH[j], acc[i][j], 0, 0, 0);
                acc[i][j] = __builtin_amdgcn_mfma_f32_16x16x32_bf16(AH[i], BL[j], acc[i][j], 0, 0, 0);
                acc[i][j] = __builtin_amdgcn_mfma_f32_16x16x32_bf16(AL[i], BH[j], acc[i][j], 0, 0, 0);
            }
    }

    // ---- epilogue: bias+relu+mask -> score partials & column sums ----
    float sp[4][4];
    float cs[4] = {0.f, 0.f, 0.f, 0.f};
#pragma unroll
    for (int i = 0; i < 4; i++)
#pragma unroll
        for (int r = 0; r < 4; r++) sp[i][r] = 0.f;

#pragma unroll
    for (int i = 0; i < 4; i++)
#pragma unroll
        for (int j = 0; j < 4; j++) {
            int c = 64 * w + 16 * j + ln;
            float bb = bsh[c], qv = qks[c];
#pragma unroll
            for (int r = 0; r < 4; r++) {
                int node = 16 * i + 4 * quad + r;
                float h = acc[i][j][r] + bb;
                h = (h > 0.f && node < nvalid) ? h : 0.f;
                sp[i][r] = fmaf(h, qv, sp[i][r]);
                cs[j] += h;
            }
        }
    // reduce score partials over ln (16 cols) in-wave
#pragma unroll
    for (int i = 0; i < 4; i++)
#pragma unroll
        for (int r = 0; r < 4; r++) {
            float s = sp[i][r];
            s += __shfl_xor(s, 1); s += __shfl_xor(s, 2);
            s += __shfl_xor(s, 4); s += __shfl_xor(s, 8);
            sp[i][r] = s;
        }
    if (ln == 0) {
#pragma unroll
        for (int i = 0; i < 4; i++)
#pragma unroll
            for (int r = 0; r < 4; r++)
                red[w][16 * i + 4 * quad + r] = sp[i][r];
    }
    // hsum: reduce over quads (nodes), one atomic per col
#pragma unroll
    for (int j = 0; j < 4; j++) {
        float s = cs[j];
        s += __shfl_xor(s, 16); s += __shfl_xor(s, 32);
        if (quad == 0) atomicAdd(&hsum[b * FD + 64 * w + 16 * j + ln], s);
    }
    __syncthreads();
    if (tid < 64 && tid < nvalid)
        scores[off + n0 + tid] = red[0][tid] + red[1][tid] + red[2][tid] + red[3][tid];
}

// ---------------------------------------------------------------------------
// K2: per-graph softmax stats + w_b = (hsum_b @ Wv + len*bv) @ Wo  (unchanged)
// ---------------------------------------------------------------------------
__global__ __launch_bounds__(1024) void k_graph(
    const float* __restrict__ scores, const float* __restrict__ hsum,
    const float* __restrict__ Wv, const float* __restrict__ bv,
    const float* __restrict__ Wo, const int* __restrict__ offsets,
    float* __restrict__ wvec, float* __restrict__ smax, float* __restrict__ dinv)
{
    int b = blockIdx.x, tid = threadIdx.x;
    int t = tid & 255, g = tid >> 8;
    int off = offsets[b], len = offsets[b + 1] - off;
    __shared__ float redm[16], reds[16];
    __shared__ float hs[FD], vs[FD];
    __shared__ float part[4][FD];

    float m = -INFINITY;
    for (int i = tid; i < len; i += 1024) m = fmaxf(m, scores[off + i]);
    for (int d = 1; d < 64; d <<= 1) m = fmaxf(m, __shfl_xor(m, d));
    if ((tid & 63) == 0) redm[tid >> 6] = m;
    __syncthreads();
    m = -INFINITY;
#pragma unroll
    for (int k = 0; k < 16; k++) m = fmaxf(m, redm[k]);

    float s = 0.f;
    for (int i = tid; i < len; i += 1024) s += expf(scores[off + i] - m);
    for (int d = 1; d < 64; d <<= 1) s += __shfl_xor(s, d);
    if ((tid & 63) == 0) reds[tid >> 6] = s;
    if (g == 0) hs[t] = hsum[b * FD + t];
    __syncthreads();
    s = 0.f;
#pragma unroll
    for (int k = 0; k < 16; k++) s += reds[k];

    float acc = (g == 0) ? (float)len * bv[t] : 0.f;
    for (int f = 64 * g; f < 64 * g + 64; f++) acc = fmaf(hs[f], Wv[f * FD + t], acc);
    part[g][t] = acc;
    __syncthreads();
    if (g == 0) vs[t] = part[0][t] + part[1][t] + part[2][t] + part[3][t];
    __syncthreads();
    float a2 = 0.f;
    for (int f = 64 * g; f < 64 * g + 64; f++) a2 = fmaf(vs[f], Wo[f * HID + t], a2);
    part[g][t] = a2;
    __syncthreads();
    if (g == 0) wvec[b * HID + t] = part[0][t] + part[1][t] + part[2][t] + part[3][t];
    if (tid == 0) { smax[b] = m; dinv[b] = 1.0f / s; }
}

// ---------------------------------------------------------------------------
// K3 (NEW): piecewise-linear walk.
// Y[n,c] = sum_k relu(p_n*w[k]+bo[k])*W2[k,c] + b2[c] is piecewise-linear in
// the scalar p_n with breakpoints t_k = -bo_k/w_k.  Per graph (1 block):
//   sort events by t, counting-sort nodes by breakpoint rank, build a merged
//   op list, then walk it from BOTH ends (fwd from the p->0+ state, bwd from
//   the p->inf state), applying rank-1 updates A += |w|*W2row, C -= |bo|*W2row
//   at events and emitting Y = p*A + C + b2 at nodes.  W2 held fp32 in LDS.
//   Exact fp32 path -> no bf16 split of W2 needed anywhere.
// ---------------------------------------------------------------------------
__global__ __launch_bounds__(256) void k_fin_walk(
    const float* __restrict__ scores, const float* __restrict__ wvec,
    const float* __restrict__ bo, const float* __restrict__ W2,
    const float* __restrict__ b2, const float* __restrict__ smax,
    const float* __restrict__ dinv, const int* __restrict__ offsets,
    float* __restrict__ Y)
{
    int b = blockIdx.x, tid = threadIdx.x;
    int off = offsets[b], len = offsets[b + 1] - off;

    __shared__ __align__(16) float W2s[HID][OUT_D];      // 131072 B, fp32 W2
    __shared__ __align__(16) char scratch[10496];        // phase-overlaid
    __shared__ float tS[HID], dwS[HID], dbS[HID];
    __shared__ int   kS[HID];
    __shared__ float wS[HID], boS[HID];
    __shared__ int   cnt[HID + 1];
    __shared__ int   startS[HID + 2];
    __shared__ float ps_s[384];
    __shared__ int   nidx_s[384], bkt[384];
    __shared__ float AINIT[4][OUT_D];
    __shared__ float b2s[OUT_D];

    // scratch overlays (phase-disjoint, barrier-separated):
    unsigned long long* ebuf = (unsigned long long*)scratch;      // P1-P3: 2048 B
    float* ptmp  = (float*)scratch;                               // P4-P6: 1536 B
    int*   rtmp  = (int*)(scratch + 1536);                        // P4-P6: 1536 B
    float4* part4 = (float4*)scratch;                             // P7:    4096 B
    float* opA = (float*)scratch;                                 // P8-P9: 2624 B
    float* opB = (float*)(scratch + 2624);
    int*   opN = (int*)(scratch + 5248);
    int*   opK = (int*)(scratch + 7872);

    float m = smax[b], di = dinv[b];

    // ---- P0: stage small vectors + full fp32 W2 into LDS ----
    float wreg = wvec[b * HID + tid];
    float breg = bo[tid];
    wS[tid] = wreg; boS[tid] = breg;
    if (tid < OUT_D) b2s[tid] = b2[tid];
    {
        const float4* gv = (const float4*)W2;
        float4* lv = (float4*)&W2s[0][0];
        for (int i = tid; i < HID * OUT_D / 4; i += 256) lv[i] = gv[i];
    }

    // ---- P1: event construction ----
    // active(k,p) := w*p+bo > 0.  Event (mask flip at t=-bo/w>0) iff w*bo<0.
    bool isev = (wreg > 0.f && breg < 0.f) || (wreg < 0.f && breg > 0.f);
    float tk = isev ? (-breg / wreg) : INFINITY;   // t>0 when real
    ebuf[tid] = ((unsigned long long)__float_as_uint(tk) << 32) | (unsigned)tid;
    int nE = __syncthreads_count(isev);
    __syncthreads();

    // ---- P2: bitonic sort 256 u64 keys ascending (t in high bits) ----
    for (int ksz = 2; ksz <= 256; ksz <<= 1) {
        for (int js = ksz >> 1; js > 0; js >>= 1) {
            int ixj = tid ^ js;
            if (ixj > tid) {
                unsigned long long a = ebuf[tid], bb2 = ebuf[ixj];
                bool sw = ((tid & ksz) == 0) ? (a > bb2) : (a < bb2);
                if (sw) { ebuf[tid] = bb2; ebuf[ixj] = a; }
            }
            __syncthreads();
        }
    }

    // ---- P3: decode sorted events; zero counters ----
    {
        unsigned long long e = ebuf[tid];
        int k = (int)(unsigned)(e & 0xffffffffULL);
        unsigned tb = (unsigned)(e >> 32);
        bool real = (tb & 0x7f800000u) != 0x7f800000u;   // finite t
        tS[tid] = __uint_as_float(tb);
        float wv = wS[k], bv = boS[k];
        dwS[tid] = real ? fabsf(wv) : 0.f;    // add-event: +w (w>0); rem-event: -w (w<0)
        dbS[tid] = real ? -fabsf(bv) : 0.f;   // add-event: +bo (bo<0); rem-event: -bo (bo>0)
        kS[tid] = k;
        cnt[tid] = 0;
        if (tid == 0) cnt[256] = 0;
    }
    __syncthreads();

    // ---- P4: per-node p, rank (= #events with t < p), histogram ----
    for (int n = tid; n < len; n += 256) {
        float p = expf(scores[off + n] - m) * di;
        int r = 0;
#pragma unroll
        for (int st = 128; st > 0; st >>= 1)
            if (tS[r + st - 1] < p) r += st;
        ptmp[n] = p; rtmp[n] = r;
        atomicAdd(&cnt[r], 1);
    }
    __syncthreads();

    // ---- P5: inclusive scan of cnt[0..255] -> bucket starts ----
    for (int d = 1; d < 256; d <<= 1) {
        int v = (tid >= d) ? cnt[tid - d] : 0;
        __syncthreads();
        cnt[tid] += v;
        __syncthreads();
    }
    startS[tid + 1] = cnt[tid];
    if (tid == 0) { startS[0] = 0; startS[257] = len; }
    __syncthreads();

    // ---- P6: counting-sort scatter of nodes by rank ----
    cnt[tid] = startS[tid];
    if (tid == 0) cnt[256] = startS[256];
    __syncthreads();
    for (int n = tid; n < len; n += 256) {
        int r = rtmp[n];
        float p = ptmp[n];
        int slot = atomicAdd(&cnt[r], 1);
        ps_s[slot] = p; nidx_s[slot] = n; bkt[slot] = r;
    }
    __syncthreads();

    // ---- P7: closed-form boundary states ----
    // A0/C0: active set at p->0+  (bo>0, or bo==0 && w>0)
    // AE/CE: active set at p->inf (w>0, plus bo-term for w==0 && bo>0)
    {
        int cI = tid & 127, hh = tid >> 7;
        float A0 = 0.f, C0 = 0.f, AE = 0.f, CE = 0.f;
        for (int k = hh * 128; k < hh * 128 + 128; ++k) {
            float vv = W2s[k][cI];
            float wv = wS[k], bv = boS[k];
            bool ini = (bv > 0.f) || (bv == 0.f && wv > 0.f);
            bool pos = (wv > 0.f);
            A0 = fmaf(ini ? wv : 0.f, vv, A0);
            C0 = fmaf(ini ? bv : 0.f, vv, C0);
            AE = fmaf(pos ? wv : 0.f, vv, AE);
            CE = fmaf((pos || (wv == 0.f && bv > 0.f)) ? bv : 0.f, vv, CE);
        }
        part4[hh * 128 + cI] = make_float4(A0, C0, AE, CE);
    }
    __syncthreads();
    if (tid < 128) {
        float4 x = part4[tid], y = part4[128 + tid];
        AINIT[0][tid] = x.x + y.x;
        AINIT[1][tid] = x.y + y.y;
        AINIT[2][tid] = x.z + y.z;
        AINIT[3][tid] = x.w + y.w;
    }
    __syncthreads();

    // ---- P8: build merged op list: bucket-j nodes, then event j ----
    int L = len + nE;
    int Lpad = (L + 7) & ~7;
    for (int s = tid; s < len; s += 256) {
        int j = bkt[s];
        int pos = s + j;
        opA[pos] = ps_s[s]; opB[pos] = 0.f; opN[pos] = nidx_s[s]; opK[pos] = 0;
    }
    for (int j = tid; j < nE; j += 256) {
        int pos = startS[j + 1] + j;
        opA[pos] = dwS[j]; opB[pos] = dbS[j]; opN[pos] = -1; opK[pos] = kS[j];
    }
    for (int i = L + tid; i < Lpad + 8; i += 256) {
        opA[i] = 0.f; opB[i] = 0.f; opN[i] = -1; opK[i] = 0;
    }
    __syncthreads();

    // ---- P9: two-ended walk.  waves 0,1: ops [0,P) fwd from (A0,C0);
    //          waves 2,3: ops [P,Lpad) bwd from (AE,CE).  Ring prefetch:
    //          scalars 8 deep, W2 rows 4 deep; all register indices static.
    {
        int lane = tid & 63;
        int c = ((tid >> 6) & 1) * 64 + lane;
        float b2v = b2s[c];
        float* Yb = Y + (size_t)off * OUT_D + c;
        int P = (L >> 1) & ~7;
        float rA[8], rB[8], rV[4]; int rN[8], rK[8];
        float A, C;
        if (tid < 128) {
            A = AINIT[0][c]; C = AINIT[1][c];
#pragma unroll
            for (int u = 0; u < 8; ++u) { rA[u]=opA[u]; rB[u]=opB[u]; rN[u]=opN[u]; rK[u]=opK[u]; }
#pragma unroll
            for (int u = 0; u < 4; ++u) rV[u] = W2s[rK[u]][c];
            for (int i0 = 0; i0 < P; i0 += 8) {
#pragma unroll
                for (int u = 0; u < 8; ++u) {
                    int i = i0 + u;
                    float aI = rA[u], bI = rB[u], vv = rV[u & 3];
                    int nI = rN[u];
                    rA[u] = opA[i + 8]; rB[u] = opB[i + 8];
                    rN[u] = opN[i + 8]; rK[u] = opK[i + 8];
                    int kpf = (u < 4) ? rK[u + 4] : rK[u - 4];   // k of op i+4
                    rV[u & 3] = W2s[kpf][c];
                    if (nI >= 0) Yb[(size_t)nI * OUT_D] = fmaf(aI, A, C) + b2v;
                    else { A = fmaf(aI, vv, A); C = fmaf(bI, vv, C); }
                }
            }
        } else {
            A = AINIT[2][c]; C = AINIT[3][c];
            int base = Lpad - 8;
#pragma unroll
            for (int u = 0; u < 8; ++u) { rA[u]=opA[base+u]; rB[u]=opB[base+u]; rN[u]=opN[base+u]; rK[u]=opK[base+u]; }
#pragma unroll
            for (int u = 0; u < 4; ++u) rV[u] = W2s[rK[u + 4]][c];
            for (int i0 = base; i0 >= P; i0 -= 8) {
#pragma unroll
                for (int uu = 0; uu < 8; ++uu) {
                    int u = 7 - uu;
                    int i = i0 + u;
                    float aI = rA[u], bI = rB[u], vv = rV[u & 3];
                    int nI = rN[u];
                    int ipf = i - 8;
                    rA[u] = opA[ipf]; rB[u] = opB[ipf];
                    rN[u] = opN[ipf]; rK[u] = opK[ipf];
                    int kpf = (u >= 4) ? rK[u - 4] : rK[u + 4];  // k of op i-4
                    rV[u & 3] = W2s[kpf][c];
                    if (nI >= 0) Yb[(size_t)nI * OUT_D] = fmaf(aI, A, C) + b2v;
                    else { A = fmaf(-aI, vv, A); C = fmaf(-bI, vv, C); }  // un-fire
                }
            }
        }
    }
}

// ---------------------------------------------------------------------------
extern "C" void kernel_launch(void* const* d_in, const int* in_sizes, int n_in,
                              void* d_out, int out_size, void* d_ws, size_t ws_size,
                              hipStream_t stream)
{
    const float* X        = (const float*)d_in[0];
    const float* text_emb = (const float*)d_in[1];
    const int*   lens     = (const int*)d_in[2];
    const float* W0       = (const float*)d_in[3];
    const float* b0       = (const float*)d_in[4];
    const float* Wq       = (const float*)d_in[5];
    const float* bq       = (const float*)d_in[6];
    const float* Wk       = (const float*)d_in[7];
    // d_in[8] = bk : softmax-invariant, unused
    const float* Wv       = (const float*)d_in[9];
    const float* bv       = (const float*)d_in[10];
    const float* Wo       = (const float*)d_in[11];
    const float* bo       = (const float*)d_in[12];
    const float* W2       = (const float*)d_in[13];
    const float* b2       = (const float*)d_in[14];
    float* Y = (float*)d_out;

    char* base = (char*)d_ws;
    size_t o = 0;
    int*   offsets = (int*)(base + o);            o += 1088;
    float* qkbuf   = (float*)(base + o);          o += 262144;
    float* wvec    = (float*)(base + o);          o += 262144;
    float* smaxb   = (float*)(base + o);          o += 1024;
    float* dinvb   = (float*)(base + o);          o += 1024;
    float* hsum    = (float*)(base + o);          o += 262144;
    float* scores  = (float*)(base + o);          o += 262144;
    unsigned short* W0sH = (unsigned short*)(base + o); o += 65536;
    unsigned short* W0sL = (unsigned short*)(base + o); o += 65536;

    k_prepA<<<261, 256, 0, stream>>>(text_emb, Wq, bq, Wk, W0, lens,
                                     qkbuf, offsets, hsum, W0sH, W0sL);
    k_l0_mfma<<<dim3(6, B_G), 256, 0, stream>>>(X, W0sH, W0sL, b0, qkbuf, offsets, scores, hsum);
    k_graph<<<B_G, 1024, 0, stream>>>(scores, hsum, Wv, bv, Wo, offsets, wvec, smaxb, dinvb);
    k_fin_walk<<<B_G, 256, 0, stream>>>(scores, wvec, bo, W2, b2, smaxb, dinvb, offsets, Y);
}

// Round 2
// 202.277 us; speedup vs baseline: 1.0985x; 1.0985x over previous
//
#include <hip/hip_runtime.h>
#include <math.h>

#define B_G   256
#define IN_D  128
#define FD    256
#define HID   256
#define OUT_D 128
#define TXT   512
#define XKS   136   // X LDS k-stride (ushorts): 272 B/row, 16B-aligned, <=2-way bank

typedef short bf16x8 __attribute__((ext_vector_type(8)));
typedef float f32x4  __attribute__((ext_vector_type(4)));

// ---------------------------------------------------------------------------
// bf16 split helpers (RNE)
// ---------------------------------------------------------------------------
__device__ __forceinline__ unsigned bf_rne(float x) {
    unsigned u = __float_as_uint(x);
    u += 0x7fffu + ((u >> 16) & 1u);
    return u >> 16;
}
__device__ __forceinline__ float bf_to_f(unsigned h) {
    return __uint_as_float(h << 16);
}
__device__ __forceinline__ void split2(float a0, float a1, unsigned& hp, unsigned& lp) {
    unsigned h0 = bf_rne(a0), h1 = bf_rne(a1);
    float r0 = a0 - bf_to_f(h0), r1 = a1 - bf_to_f(h1);
    hp = h0 | (h1 << 16);
    lp = bf_rne(r0) | (bf_rne(r1) << 16);
}

// ---------------------------------------------------------------------------
// Kernel A (grid 261): fused prep.  (unchanged)
// ---------------------------------------------------------------------------
__global__ __launch_bounds__(256) void k_prepA(
    const float* __restrict__ text_emb, const float* __restrict__ Wq,
    const float* __restrict__ bq, const float* __restrict__ Wk,
    const float* __restrict__ W0, const int* __restrict__ lens,
    float* __restrict__ qk, int* __restrict__ offsets, float* __restrict__ hsum,
    unsigned short* __restrict__ W0sH, unsigned short* __restrict__ W0sL)
{
    int blk = blockIdx.x, t = threadIdx.x;
    __shared__ float te[TXT];
    __shared__ float q[FD];
    __shared__ int   sc[B_G];

    if (blk < 256) {
        int b = blk;
        hsum[b * FD + t] = 0.f;
        for (int i = t; i < TXT; i += 256) te[i] = text_emb[(size_t)b * TXT + i];
        __syncthreads();
        float acc = bq[t];
        for (int k = 0; k < TXT; k++) acc = fmaf(te[k], Wq[k * FD + t], acc);
        q[t] = acc;
        __syncthreads();
        float a2 = 0.f;
        for (int f = 0; f < FD; f++) a2 = fmaf(Wk[t * FD + f], q[f], a2);
        qk[b * FD + t] = a2;
    } else if (blk < 260) {
        int e = (blk - 256) * 256 + t;   // 0..1023
        int kc = e >> 8, c = e & 255;
        size_t base = (size_t)(kc * 256 + c) * 32;
        for (int kk = 0; kk < 32; kk++) {
            float v = W0[(size_t)(kc * 32 + kk) * FD + c];
            unsigned h = bf_rne(v);
            float r = v - bf_to_f(h);
            W0sH[base + kk] = (unsigned short)h;
            W0sL[base + kk] = (unsigned short)bf_rne(r);
        }
    } else {
        // parallel inclusive scan of lens (256 elements, 8 steps)
        sc[t] = lens[t];
        __syncthreads();
        for (int d = 1; d < 256; d <<= 1) {
            int v = (t >= d) ? sc[t - d] : 0;
            __syncthreads();
            sc[t] += v;
            __syncthreads();
        }
        offsets[t + 1] = sc[t];
        if (t == 0) offsets[0] = 0;
    }
}

// ---------------------------------------------------------------------------
// K1: bf16x3 MFMA, barrier-free K-loop.  (unchanged)
// ---------------------------------------------------------------------------
__global__ __launch_bounds__(256, 2) void k_l0_mfma(
    const float* __restrict__ X,
    const unsigned short* __restrict__ W0sH, const unsigned short* __restrict__ W0sL,
    const float* __restrict__ b0, const float* __restrict__ qk,
    const int* __restrict__ offsets,
    float* __restrict__ scores, float* __restrict__ hsum)
{
    int b = blockIdx.y;
    int off = offsets[b], len = offsets[b + 1] - off;
    int n0 = blockIdx.x * 64;
    if (n0 >= len) return;
    int nvalid = min(64, len - n0);

    __shared__ __align__(16) unsigned short XsH[64 * XKS], XsL[64 * XKS]; // 2x17408 B
    __shared__ float qks[FD];
    __shared__ float bsh[FD];
    __shared__ float red[4][64];

    int tid = threadIdx.x;
    int lane = tid & 63, w = tid >> 6;
    int ln = lane & 15, quad = lane >> 4;

    qks[tid] = qk[b * FD + tid];
    bsh[tid] = b0[tid];

    // ---- stage X (full K) : thread -> node tid>>2, k-range (tid&3)*32..+32 ----
    {
        int node_s = tid >> 2, ks = (tid & 3) * 32;
        const float* Xr = X + (size_t)(off + n0 + node_s) * IN_D + ks;
        float xv[32];
        if (node_s < nvalid) {
#pragma unroll
            for (int q2 = 0; q2 < 8; q2++) {
                float4 v = ((const float4*)Xr)[q2];
                xv[q2 * 4 + 0] = v.x; xv[q2 * 4 + 1] = v.y;
                xv[q2 * 4 + 2] = v.z; xv[q2 * 4 + 3] = v.w;
            }
        } else {
#pragma unroll
            for (int q2 = 0; q2 < 32; q2++) xv[q2] = 0.f;
        }
#pragma unroll
        for (int g = 0; g < 4; g++) {
            uint4 hq, lq;
            split2(xv[g * 8 + 0], xv[g * 8 + 1], hq.x, lq.x);
            split2(xv[g * 8 + 2], xv[g * 8 + 3], hq.y, lq.y);
            split2(xv[g * 8 + 4], xv[g * 8 + 5], hq.z, lq.z);
            split2(xv[g * 8 + 6], xv[g * 8 + 7], hq.w, lq.w);
            *(uint4*)&XsH[node_s * XKS + ks + g * 8] = hq;
            *(uint4*)&XsL[node_s * XKS + ks + g * 8] = lq;
        }
    }
    __syncthreads();

    f32x4 acc[4][4] = {};
#pragma unroll
    for (int kc = 0; kc < 4; kc++) {
        bf16x8 AH[4], AL[4], BH[4], BL[4];
#pragma unroll
        for (int i = 0; i < 4; i++) {
            AH[i] = *(const bf16x8*)&XsH[(16 * i + ln) * XKS + kc * 32 + quad * 8];
            AL[i] = *(const bf16x8*)&XsL[(16 * i + ln) * XKS + kc * 32 + quad * 8];
        }
#pragma unroll
        for (int j = 0; j < 4; j++) {
            int c = 64 * w + 16 * j + ln;
            size_t base = (size_t)(kc * 256 + c) * 32 + quad * 8;
            BH[j] = *(const bf16x8*)&W0sH[base];
            BL[j] = *(const bf16x8*)&W0sL[base];
        }
#pragma unroll
        for (int i = 0; i < 4; i++)
#pragma unroll
            for (int j = 0; j < 4; j++) {
                acc[i][j] = __builtin_amdgcn_mfma_f32_16x16x32_bf16(AH[i], BH[j], acc[i][j], 0, 0, 0);
                acc[i][j] = __builtin_amdgcn_mfma_f32_16x16x32_bf16(AH[i], BL[j], acc[i][j], 0, 0, 0);
                acc[i][j] = __builtin_amdgcn_mfma_f32_16x16x32_bf16(AL[i], BH[j], acc[i][j], 0, 0, 0);
            }
    }

    // ---- epilogue: bias+relu+mask -> score partials & column sums ----
    float sp[4][4];
    float cs[4] = {0.f, 0.f, 0.f, 0.f};
#pragma unroll
    for (int i = 0; i < 4; i++)
#pragma unroll
        for (int r = 0; r < 4; r++) sp[i][r] = 0.f;

#pragma unroll
    for (int i = 0; i < 4; i++)
#pragma unroll
        for (int j = 0; j < 4; j++) {
            int c = 64 * w + 16 * j + ln;
            float bb = bsh[c], qv = qks[c];
#pragma unroll
            for (int r = 0; r < 4; r++) {
                int node = 16 * i + 4 * quad + r;
                float h = acc[i][j][r] + bb;
                h = (h > 0.f && node < nvalid) ? h : 0.f;
                sp[i][r] = fmaf(h, qv, sp[i][r]);
                cs[j] += h;
            }
        }
    // reduce score partials over ln (16 cols) in-wave
#pragma unroll
    for (int i = 0; i < 4; i++)
#pragma unroll
        for (int r = 0; r < 4; r++) {
            float s = sp[i][r];
            s += __shfl_xor(s, 1); s += __shfl_xor(s, 2);
            s += __shfl_xor(s, 4); s += __shfl_xor(s, 8);
            sp[i][r] = s;
        }
    if (ln == 0) {
#pragma unroll
        for (int i = 0; i < 4; i++)
#pragma unroll
            for (int r = 0; r < 4; r++)
                red[w][16 * i + 4 * quad + r] = sp[i][r];
    }
    // hsum: reduce over quads (nodes), one atomic per col
#pragma unroll
    for (int j = 0; j < 4; j++) {
        float s = cs[j];
        s += __shfl_xor(s, 16); s += __shfl_xor(s, 32);
        if (quad == 0) atomicAdd(&hsum[b * FD + 64 * w + 16 * j + ln], s);
    }
    __syncthreads();
    if (tid < 64 && tid < nvalid)
        scores[off + n0 + tid] = red[0][tid] + red[1][tid] + red[2][tid] + red[3][tid];
}

// ---------------------------------------------------------------------------
// K2: per-graph softmax stats + w_b = (hsum_b @ Wv + len*bv) @ Wo  (unchanged)
// ---------------------------------------------------------------------------
__global__ __launch_bounds__(1024) void k_graph(
    const float* __restrict__ scores, const float* __restrict__ hsum,
    const float* __restrict__ Wv, const float* __restrict__ bv,
    const float* __restrict__ Wo, const int* __restrict__ offsets,
    float* __restrict__ wvec, float* __restrict__ smax, float* __restrict__ dinv)
{
    int b = blockIdx.x, tid = threadIdx.x;
    int t = tid & 255, g = tid >> 8;
    int off = offsets[b], len = offsets[b + 1] - off;
    __shared__ float redm[16], reds[16];
    __shared__ float hs[FD], vs[FD];
    __shared__ float part[4][FD];

    float m = -INFINITY;
    for (int i = tid; i < len; i += 1024) m = fmaxf(m, scores[off + i]);
    for (int d = 1; d < 64; d <<= 1) m = fmaxf(m, __shfl_xor(m, d));
    if ((tid & 63) == 0) redm[tid >> 6] = m;
    __syncthreads();
    m = -INFINITY;
#pragma unroll
    for (int k = 0; k < 16; k++) m = fmaxf(m, redm[k]);

    float s = 0.f;
    for (int i = tid; i < len; i += 1024) s += expf(scores[off + i] - m);
    for (int d = 1; d < 64; d <<= 1) s += __shfl_xor(s, d);
    if ((tid & 63) == 0) reds[tid >> 6] = s;
    if (g == 0) hs[t] = hsum[b * FD + t];
    __syncthreads();
    s = 0.f;
#pragma unroll
    for (int k = 0; k < 16; k++) s += reds[k];

    float acc = (g == 0) ? (float)len * bv[t] : 0.f;
    for (int f = 64 * g; f < 64 * g + 64; f++) acc = fmaf(hs[f], Wv[f * FD + t], acc);
    part[g][t] = acc;
    __syncthreads();
    if (g == 0) vs[t] = part[0][t] + part[1][t] + part[2][t] + part[3][t];
    __syncthreads();
    float a2 = 0.f;
    for (int f = 64 * g; f < 64 * g + 64; f++) a2 = fmaf(vs[f], Wo[f * HID + t], a2);
    part[g][t] = a2;
    __syncthreads();
    if (g == 0) wvec[b * HID + t] = part[0][t] + part[1][t] + part[2][t] + part[3][t];
    if (tid == 0) { smax[b] = m; dinv[b] = 1.0f / s; }
}

// ---------------------------------------------------------------------------
// K3: piecewise-linear walk, v2 (latency-tolerant).
//  Y[n,c] = p_n*A(p_n)[c] + C(p_n)[c] + b2[c], A/C piecewise-constant with
//  <=256 breakpoints t_k = -bo_k/w_k.  Per graph, 1024 threads:
//   - rank-compare "sort" of events (O(256) loop, 1 barrier; no bitonic)
//   - one node per thread: p, rank via binary search, counting-sort into a
//     merged op list (nodes bucketed between events)
//   - op list split into 8 segments; per-segment event-delta sums computed in
//     parallel, 8-wide per-column scan, then 8x128 concurrent segment walks.
//  W2 stays in global (L2-hot, 128 KB shared by all blocks) -> LDS ~29 KB,
//  16 waves/CU.  fp32-exact final layer.
// ---------------------------------------------------------------------------
__global__ __launch_bounds__(1024) void k_fin_walk(
    const float* __restrict__ scores, const float* __restrict__ wvec,
    const float* __restrict__ bo, const float* __restrict__ W2,
    const float* __restrict__ b2, const float* __restrict__ smax,
    const float* __restrict__ dinv, const int* __restrict__ offsets,
    float* __restrict__ Y)
{
    int b = blockIdx.x, tid = threadIdx.x;
    int off = offsets[b], len = offsets[b + 1] - off;

    __shared__ float tOrig[256];                 // per-original-k breakpoint (INF if none)
    __shared__ float tS[256], dwS[256], dbS[256];// sorted events
    __shared__ int   kS[256];
    __shared__ float wS[256], boS[256];
    __shared__ int   cnt[257], startS[257];
    __shared__ float A0s[OUT_D], C0s[OUT_D], b2s[OUT_D];
    __shared__ float segA[8][OUT_D], segC[8][OUT_D];
    __shared__ __align__(16) char ops_raw[656 * 16];
    float* opA = (float*)ops_raw;                // [656]
    float* opB = (float*)(ops_raw + 2624);       // [656]
    int*   opN = (int*)(ops_raw + 5248);         // [656]
    int*   opK = (int*)(ops_raw + 7872);         // [656]

    float m = smax[b], di = dinv[b];

    // ---- P0: stage vectors, zero counters, build own event ----
    bool real = false;
    if (tid < 256) {
        float wv = wvec[b * HID + tid];
        float bv = bo[tid];
        wS[tid] = wv; boS[tid] = bv;
        bool isev = (wv > 0.f && bv < 0.f) || (wv < 0.f && bv > 0.f);
        float tk = isev ? (-bv / wv) : INFINITY;
        real = isev && (tk < INFINITY);
        tOrig[tid] = real ? tk : INFINITY;
        cnt[tid] = 0;
        if (tid == 0) cnt[256] = 0;
    }
    if (tid < OUT_D) b2s[tid] = b2[tid];
    __syncthreads();

    // ---- P1: rank-compare sort of events + boundary partials (A0/C0) ----
    if (tid < 256) {
        float tk = tOrig[tid];
        int r = 0;
        for (int j = 0; j < 256; j++) {
            float tj = tOrig[j];
            r += (tj < tk || (tj == tk && j < tid)) ? 1 : 0;
        }
        tS[r] = tk;
        kS[r] = tid;
        float wv = wS[tid], bv = boS[tid];
        dwS[r] = real ? fabsf(wv) : 0.f;   // add-event (w>0): +w ; remove-event (w<0): -w
        dbS[r] = real ? -fabsf(bv) : 0.f;  // add-event: +bo (bo<0) ; remove-event: -bo (bo>0)
    }
    // A0/C0 partials: active set at p->0+ is {k: bo>0 or (bo==0 && w>0)}
    {
        int q = tid >> 7, c = tid & 127;
        float pa = 0.f, pc = 0.f;
        for (int k = q * 32; k < q * 32 + 32; ++k) {
            float v = W2[(size_t)k * OUT_D + c];
            float wv = wS[k], bv = boS[k];
            bool ini = (bv > 0.f) || (bv == 0.f && wv > 0.f);
            pa = fmaf(ini ? wv : 0.f, v, pa);
            pc = fmaf(ini ? bv : 0.f, v, pc);
        }
        segA[q][c] = pa; segC[q][c] = pc;
    }
    int nE = __syncthreads_count(real);   // barrier + event count

    // ---- P2: per-node p + rank; histogram.  A0/C0 reduce on tid<128. ----
    float p_n = 0.f; int r_n = 0;
    if (tid < len) {
        p_n = expf(scores[off + tid] - m) * di;
        int r = 0;
#pragma unroll
        for (int st = 128; st > 0; st >>= 1)
            if (tS[r + st - 1] < p_n) r += st;
        r_n = r;
        atomicAdd(&cnt[r], 1);
    }
    if (tid < OUT_D) {
        float sa = 0.f, sc2 = 0.f;
#pragma unroll
        for (int q = 0; q < 8; q++) { sa += segA[q][tid]; sc2 += segC[q][tid]; }
        A0s[tid] = sa; C0s[tid] = sc2;
    }
    __syncthreads();

    // ---- P3: exclusive-scan of cnt[0..255] by wave 0 (shfl, no barriers) ----
    if (tid < 64) {
        int l = tid;
        int v0 = cnt[4 * l], v1 = cnt[4 * l + 1], v2 = cnt[4 * l + 2], v3 = cnt[4 * l + 3];
        int s0 = v0, s1 = s0 + v1, s2 = s1 + v2, s3 = s2 + v3;
        int run = s3;
#pragma unroll
        for (int d = 1; d < 64; d <<= 1) {
            int t2 = __shfl_up(run, d);
            if (l >= d) run += t2;
        }
        int base = run - s3;   // exclusive over lanes
        startS[4 * l + 0] = base;      cnt[4 * l + 0] = base;
        startS[4 * l + 1] = base + s0; cnt[4 * l + 1] = base + s0;
        startS[4 * l + 2] = base + s1; cnt[4 * l + 2] = base + s1;
        startS[4 * l + 3] = base + s2; cnt[4 * l + 3] = base + s2;
        if (l == 63) { startS[256] = base + s3; cnt[256] = base + s3; }
    }
    __syncthreads();

    int L    = len + nE;
    int Lpad = (L + 7) & ~7;
    int Lseg = ((Lpad + 63) >> 6) << 3;   // ceil(Lpad/8) rounded up to mult of 8; <=80

    // ---- P4: build merged op list (nodes scatter + events + padding) ----
    if (tid < len) {
        int slot = atomicAdd(&cnt[r_n], 1);
        int pos = slot + r_n;
        opA[pos] = p_n; opB[pos] = 0.f; opN[pos] = tid; opK[pos] = 0;
    }
    if (tid < nE) {
        int pos = startS[tid + 1] + tid;
        opA[pos] = dwS[tid]; opB[pos] = dbS[tid]; opN[pos] = -1; opK[pos] = kS[tid];
    }
    for (int i = L + tid; i < 648; i += 1024) {
        opA[i] = 0.f; opB[i] = 0.f; opN[i] = -1; opK[i] = 0;
    }
    __syncthreads();

    // ---- P5: per-segment event-delta sums (events in a segment are a
    //          contiguous j-range since pos(j)=startS[j+1]+j is monotone) ----
    int s = tid >> 7, c = tid & 127;
    {
        int iBeg = s * Lseg, iEnd = iBeg + Lseg;
        // binary search smallest j with pos(j) >= iBeg
        int lo = 0, hi = nE;
        while (lo < hi) {
            int mid = (lo + hi) >> 1;
            if (startS[mid + 1] + mid < iBeg) lo = mid + 1; else hi = mid;
        }
        float dA = 0.f, dC = 0.f;
        for (int j = lo; j < nE && (startS[j + 1] + j) < iEnd; ++j) {
            float v = W2[(size_t)kS[j] * OUT_D + c];
            dA = fmaf(dwS[j], v, dA);
            dC = fmaf(dbS[j], v, dC);
        }
        segA[s][c] = dA; segC[s][c] = dC;
    }
    __syncthreads();

    // ---- P6: segment walks.  Thread (s,c): start state = A0 + prefix of
    //          segment deltas; ring-prefetch ops (8 deep) + W2 rows (8 deep).
    {
        float A = A0s[c], C = C0s[c];
        for (int s2 = 0; s2 < s; ++s2) { A += segA[s2][c]; C += segC[s2][c]; }
        float b2v = b2s[c];
        float* Yb = Y + (size_t)off * OUT_D + c;
        int i0 = s * Lseg;

        float rA[8], rB[8], rV[8]; int rN[8], rK[8];
#pragma unroll
        for (int u = 0; u < 8; ++u) {
            rA[u] = opA[i0 + u]; rB[u] = opB[i0 + u];
            rN[u] = opN[i0 + u]; rK[u] = opK[i0 + u];
        }
#pragma unroll
        for (int u = 0; u < 8; ++u) rV[u] = W2[(size_t)rK[u] * OUT_D + c];

        for (int i0w = i0; i0w < i0 + Lseg; i0w += 8) {
#pragma unroll
            for (int u = 0; u < 8; ++u) {
                int i = i0w + u;
                float aI = rA[u], bI = rB[u], vv = rV[u];
                int nI = rN[u];
                rA[u] = opA[i + 8]; rB[u] = opB[i + 8];
                rN[u] = opN[i + 8]; rK[u] = opK[i + 8];
                rV[u] = W2[(size_t)rK[u] * OUT_D + c];
                if (nI >= 0) Yb[(size_t)nI * OUT_D] = fmaf(aI, A, C) + b2v;
                else { A = fmaf(aI, vv, A); C = fmaf(bI, vv, C); }
            }
        }
    }
}

// ---------------------------------------------------------------------------
extern "C" void kernel_launch(void* const* d_in, const int* in_sizes, int n_in,
                              void* d_out, int out_size, void* d_ws, size_t ws_size,
                              hipStream_t stream)
{
    const float* X        = (const float*)d_in[0];
    const float* text_emb = (const float*)d_in[1];
    const int*   lens     = (const int*)d_in[2];
    const float* W0       = (const float*)d_in[3];
    const float* b0       = (const float*)d_in[4];
    const float* Wq       = (const float*)d_in[5];
    const float* bq       = (const float*)d_in[6];
    const float* Wk       = (const float*)d_in[7];
    // d_in[8] = bk : softmax-invariant, unused
    const float* Wv       = (const float*)d_in[9];
    const float* bv       = (const float*)d_in[10];
    const float* Wo       = (const float*)d_in[11];
    const float* bo       = (const float*)d_in[12];
    const float* W2       = (const float*)d_in[13];
    const float* b2       = (const float*)d_in[14];
    float* Y = (float*)d_out;

    char* base = (char*)d_ws;
    size_t o = 0;
    int*   offsets = (int*)(base + o);            o += 1088;
    float* qkbuf   = (float*)(base + o);          o += 262144;
    float* wvec    = (float*)(base + o);          o += 262144;
    float* smaxb   = (float*)(base + o);          o += 1024;
    float* dinvb   = (float*)(base + o);          o += 1024;
    float* hsum    = (float*)(base + o);          o += 262144;
    float* scores  = (float*)(base + o);          o += 262144;
    unsigned short* W0sH = (unsigned short*)(base + o); o += 65536;
    unsigned short* W0sL = (unsigned short*)(base + o); o += 65536;

    k_prepA<<<261, 256, 0, stream>>>(text_emb, Wq, bq, Wk, W0, lens,
                                     qkbuf, offsets, hsum, W0sH, W0sL);
    k_l0_mfma<<<dim3(6, B_G), 256, 0, stream>>>(X, W0sH, W0sL, b0, qkbuf, offsets, scores, hsum);
    k_graph<<<B_G, 1024, 0, stream>>>(scores, hsum, Wv, bv, Wo, offsets, wvec, smaxb, dinvb);
    k_fin_walk<<<B_G, 1024, 0, stream>>>(scores, wvec, bo, W2, b2, smaxb, dinvb, offsets, Y);
}